// Round 12
// baseline (1572.774 us; speedup 1.0000x reference)
//
#include <hip/hip_runtime.h>
#include <hip/hip_fp8.h>

// CausalConv3dFP8 round 12: r11 + A-operand software pipeline.
// launch_bounds(256,2) -> 256 VGPR budget; A[2][6] register double-buffer:
// load tier t+1's 6 A-frags (L2) under tier t's 12 MFMAs; cross-phase prefetch.
// dbuf LDS staged by global_load_lds, counted vmcnt(9), split-half layout,
// kd-skip, bijective XCD h-band swizzle.
// xq layout: [b][d4][hp194][ci32 grp 4][wp322][32B]
// wpk layout: [tap27][cc2][cq4][lane64][32B]

using f32x16 = __attribute__((ext_vector_type(16))) float;
using i32x8 = __attribute__((ext_vector_type(8))) int;
using i32x4 = __attribute__((ext_vector_type(4))) int;
typedef long long i64;
struct alignas(16) L2v { i64 x, y; };

namespace {
constexpr int Cc = 128, Dd = 4, Hh = 192, Ww = 320;
constexpr int HP = 194, WP = 322;
constexpr int NTAP = 27;
constexpr size_t PLANE = (size_t)4 * WP * 32;               // 41,216 B per (b,d,h) row-plane
constexpr size_t XQ_BYTES = (size_t)2 * Dd * HP * PLANE;    // 63,967,232
constexpr int ZA = 8 * 2 * 2576;
constexpr int ZB = 8 * 192 * 32;
constexpr int GSTR = WP * 32;                               // 10,304 B per ci32-group
constexpr int HB = 1056;                                    // 66*16: half-plane stride in LDS
constexpr int BUFB = 2112 * 16;                             // 33,792 B per LDS buffer
constexpr int KDSTR = 9 * 2 * 4 * 64 * 32;                  // 147,456 B per kd in wpk
}

__global__ __launch_bounds__(256) void zero_pad_kernel(unsigned char* __restrict__ xq) {
  int i = blockIdx.x * 256 + threadIdx.x;
  if (i < ZA) {
    int bd = i / (2 * 2576);
    int r = i - bd * (2 * 2576);
    int hsel = r / 2576, seg = r - hsel * 2576;
    L2v z{0, 0};
    *(L2v*)(xq + ((size_t)bd * HP + (hsel ? 193 : 0)) * PLANE + (size_t)seg * 16) = z;
  } else if (i < ZA + ZB) {
    int j = i - ZA;
    int bd = j / (192 * 32);
    int r = j - bd * (192 * 32);
    int h = r / 32 + 1;
    int t = r & 31;
    int g = t >> 3, s2 = t & 7;
    int wsel = s2 >> 2, part = s2 & 3;
    *(i64*)(xq + ((size_t)bd * HP + h) * PLANE + (size_t)g * GSTR
            + (size_t)(wsel ? 321 : 0) * 32 + part * 8) = 0;
  }
}

__global__ __launch_bounds__(256) void qx_kernel(const float* __restrict__ x,
                                                 unsigned char* __restrict__ xq) {
  __shared__ unsigned char lt[64 * 136];
  const int tid = threadIdx.x;
  const int b = blockIdx.z >> 2, d = blockIdx.z & 3;
  const int h = blockIdx.y;
  const int w0 = blockIdx.x * 64;
  const int wl = tid & 63, cig = tid >> 6;
  const size_t cstr = (size_t)Dd * Hh * Ww;
  const float* xp = x + (((size_t)b * Cc * Dd + d) * Hh + h) * Ww + w0 + wl;
  #pragma unroll 4
  for (int i = 0; i < 32; ++i) {
    int ci = cig * 32 + i;
    __hip_fp8_e4m3 q(xp[ci * cstr]);
    lt[wl * 136 + ci] = q.__x;
  }
  __syncthreads();
  unsigned char* plane = xq + ((size_t)(b * Dd + d) * HP + h + 1) * PLANE;
  {
    int g = tid >> 6, w = tid & 63;
    const unsigned char* src = lt + w * 136 + g * 32;
    i64 a0 = *(const i64*)(src), a1 = *(const i64*)(src + 8);
    i64 a2 = *(const i64*)(src + 16), a3 = *(const i64*)(src + 24);
    unsigned char* dst = plane + (size_t)g * GSTR + (size_t)(w0 + 1 + w) * 32;
    *(L2v*)dst = L2v{a0, a1};
    *(L2v*)(dst + 16) = L2v{a2, a3};
  }
}

__global__ void wpack_kernel(const float* __restrict__ w, unsigned char* __restrict__ wpk) {
  int idx = blockIdx.x * 256 + threadIdx.x;
  if (idx >= Cc * Cc * NTAP) return;
  int tap = idx % NTAP;
  int t = idx / NTAP;
  int ci = t % Cc, co = t / Cc;
  int cc = ci >> 6, cq = co >> 5;
  int lane = (((ci >> 5) & 1) << 5) | (co & 31);
  __hip_fp8_e4m3 q(w[idx]);
  wpk[((((size_t)tap * 2 + cc) * 4 + cq) * 64 + lane) * 32 + (ci & 31)] = q.__x;
}

__device__ __forceinline__ void gll16(const unsigned char* g, unsigned char* l) {
  __builtin_amdgcn_global_load_lds(
      (const __attribute__((address_space(1))) void*)g,
      (__attribute__((address_space(3))) void*)l, 16, 0, 0);
}
__device__ __forceinline__ void gll4(const unsigned char* g, unsigned char* l) {
  __builtin_amdgcn_global_load_lds(
      (const __attribute__((address_space(1))) void*)g,
      (__attribute__((address_space(3))) void*)l, 4, 0, 0);
}

__global__ __launch_bounds__(256, 2) void conv_mfma(const unsigned char* __restrict__ xq,
                                                    const unsigned char* __restrict__ wpk,
                                                    float* __restrict__ out) {
  __shared__ unsigned char lb[2 * BUFB];           // dbuf x [hrow4][g4][half2][66w][16B]
  const int tid = threadIdx.x;
  const int lane = tid & 63, wv = tid >> 6;
  const int l31 = lane & 31, chalf = lane >> 5;
  const int hr = wv >> 1, ch = wv & 1;             // wave: h-row, cout-half (64 co)
  // ---- bijective XCD h-band swizzle ----
  const int id = blockIdx.x;
  const int xcd = id & 7, j = id >> 3;
  const int h0l = j / 40, rem = j - h0l * 40;
  const int z = rem / 5, wx = rem - z * 5;
  const int b = z >> 2, dout = z & 3;
  const int h0 = (xcd * 12 + h0l) * 2;
  const int w0 = wx * 64;
  const int kdmin = dout >= 2 ? 0 : 2 - dout;

  // ---- per-thread staging descriptors ----
  size_t off16[8];
  int lds16[8];
  #pragma unroll
  for (int it = 0; it < 8; ++it) {
    int u = it * 256 + tid;
    int rh = u / 66, w = u - rh * 66;
    int half = rh & 1, rg = rh >> 1;
    int g = rg & 3, hrow = rg >> 2;
    off16[it] = (size_t)(h0 + hrow) * PLANE + (size_t)g * GSTR
                + (size_t)(w0 + w) * 32 + half * 16;
    lds16[it] = u * 16;
  }
  size_t off4;
  int lds4 = 32768 + tid * 4;
  {
    int q = 2048 + (tid >> 2);
    int rh = q / 66, w = q - rh * 66;
    int half = rh & 1, rg = rh >> 1;
    int g = rg & 3, hrow = rg >> 2;
    off4 = (size_t)(h0 + hrow) * PLANE + (size_t)g * GSTR
           + (size_t)(w0 + w) * 32 + half * 16 + (tid & 3) * 4;
  }
  const long img0 = (long)(b * Dd + dout - 2) * (long)(HP * PLANE);
  const long imgstep = (long)HP * PLANE;

  // A-fragment base: per-lane term + cout-half term (tier offsets are compile-time)
  const unsigned char* vbase = wpk + ch * 2 * 2048 + lane * 32;

  f32x16 acc[2][2];                                // [ct][nf]
  #pragma unroll
  for (int a = 0; a < 2; ++a)
    #pragma unroll
    for (int n = 0; n < 2; ++n)
      #pragma unroll
      for (int r = 0; r < 16; ++r) acc[a][n][r] = 0.f;

  i32x8 A[2][6];                                   // [parity][kw*2+ct]

  // ---- prologue: stage first kd into buf0; prefetch tier0 A-frags ----
  {
    const unsigned char* img = xq + img0 + (long)kdmin * imgstep;
    #pragma unroll
    for (int it = 0; it < 8; ++it) gll16(img + off16[it], lb + lds16[it]);
    gll4(img + off4, lb + lds4);
    const unsigned char* wkd0 = vbase + kdmin * KDSTR;
    #pragma unroll
    for (int kw = 0; kw < 3; ++kw)
      #pragma unroll
      for (int ct = 0; ct < 2; ++ct)
        A[0][kw * 2 + ct] = *(const i32x8*)(wkd0 + (kw * 2) * 8192 + ct * 2048);
  }

  int p = 0;
  for (int kd = kdmin; kd < 3; ++kd) {
    const unsigned char* wkd = vbase + kd * KDSTR;
    if (kd + 1 < 3) {
      const unsigned char* img = xq + img0 + (long)(kd + 1) * imgstep;
      unsigned char* bufn = lb + (p ? 0 : BUFB);
      #pragma unroll
      for (int it = 0; it < 8; ++it) gll16(img + off16[it], bufn + lds16[it]);
      gll4(img + off4, bufn + lds4);
      asm volatile("s_waitcnt vmcnt(9)" ::: "memory");
    } else {
      asm volatile("s_waitcnt vmcnt(0)" ::: "memory");
    }
    __builtin_amdgcn_s_barrier();
    __builtin_amdgcn_sched_barrier(0);

    const unsigned char* bufp = lb + (p ? BUFB : 0);
    const unsigned char* bb[3];
    #pragma unroll
    for (int kw = 0; kw < 3; ++kw)
      bb[kw] = bufp + (hr * 4 + chalf) * 2 * HB + (l31 + kw) * 16;

    __builtin_amdgcn_s_setprio(1);
    #pragma unroll
    for (int t = 0; t < 6; ++t) {                  // tier t = kh*2 + cc
      // ---- prefetch next tier's A-frags into the other parity ----
      if (t < 5) {
        const int tn = t + 1;
        const int khn = tn >> 1, ccn = tn & 1;
        #pragma unroll
        for (int kw = 0; kw < 3; ++kw)
          #pragma unroll
          for (int ct = 0; ct < 2; ++ct)
            A[tn & 1][kw * 2 + ct] =
                *(const i32x8*)(wkd + ((khn * 3 + kw) * 2 + ccn) * 8192 + ct * 2048);
      } else if (kd + 1 < 3) {
        #pragma unroll
        for (int kw = 0; kw < 3; ++kw)
          #pragma unroll
          for (int ct = 0; ct < 2; ++ct)
            A[0][kw * 2 + ct] =
                *(const i32x8*)(wkd + KDSTR + (kw * 2) * 8192 + ct * 2048);
      }
      // ---- compute tier t ----
      const int kh = t >> 1, cc = t & 1;
      #pragma unroll
      for (int kw = 0; kw < 3; ++kw)
        #pragma unroll
        for (int nf = 0; nf < 2; ++nf) {
          const int off = (kh * 4 + cc * 2) * 2 * HB + nf * 512;
          i32x4 blo = *(const i32x4*)(bb[kw] + off);
          i32x4 bhi = *(const i32x4*)(bb[kw] + off + HB);
          i32x8 bv = __builtin_shufflevector(blo, bhi, 0, 1, 2, 3, 4, 5, 6, 7);
          #pragma unroll
          for (int ct = 0; ct < 2; ++ct)
            acc[ct][nf] = __builtin_amdgcn_mfma_scale_f32_32x32x64_f8f6f4(
                A[t & 1][kw * 2 + ct], bv, acc[ct][nf], 0, 0, 0, 127, 0, 127);
        }
    }
    __builtin_amdgcn_s_setprio(0);
    __builtin_amdgcn_s_barrier();
    p ^= 1;
  }

  // ---- epilogue: col=l31 -> w, row=(reg&3)+8*(reg>>2)+4*chalf -> cout ----
  #pragma unroll
  for (int ct = 0; ct < 2; ++ct)
    #pragma unroll
    for (int nf = 0; nf < 2; ++nf) {
      int ww = w0 + nf * 32 + l31;
      #pragma unroll
      for (int reg = 0; reg < 16; ++reg) {
        int co = ch * 64 + ct * 32 + (reg & 3) + 8 * (reg >> 2) + 4 * chalf;
        out[(((size_t)b * Cc + co) * Dd + dout) * (size_t)(Hh * Ww)
            + (size_t)(h0 + hr) * Ww + ww] = acc[ct][nf][reg];
      }
    }
}

extern "C" void kernel_launch(void* const* d_in, const int* in_sizes, int n_in,
                              void* d_out, int out_size, void* d_ws, size_t ws_size,
                              hipStream_t stream) {
  const float* x = (const float*)d_in[0];
  const float* w = (const float*)d_in[1];
  unsigned char* xq = (unsigned char*)d_ws;
  unsigned char* wpk = xq + XQ_BYTES;              // 442,368 B
  float* out = (float*)d_out;

  int nz = ZA + ZB;
  zero_pad_kernel<<<(nz + 255) / 256, 256, 0, stream>>>(xq);

  dim3 g1(Ww / 64, Hh, 2 * Dd);
  qx_kernel<<<g1, 256, 0, stream>>>(x, xq);

  int nw = Cc * Cc * NTAP;
  wpack_kernel<<<(nw + 255) / 256, 256, 0, stream>>>(w, wpk);

  conv_mfma<<<dim3(3840), 256, 0, stream>>>(xq, wpk, out);
}

// Round 13
// 473.364 us; speedup vs baseline: 3.3225x; 3.3225x over previous
//
#include <hip/hip_runtime.h>
#include <hip/hip_fp8.h>

// CausalConv3dFP8 round 13: revert r12 spill disaster. A-traffic fix via tile shape:
// wave = 64co x 64w x 2h (block 128co x 64w x 4h) -> each A-frag reused x4
// (nf2 x hl2) -> 512 B/MFMA from L2 (~30 B/cyc < 56 B/cyc L2 supply).
// acc 128 AGPR, LDS single-buffer 50.7KB [hrow6][g4][half2][66w][16B], gll staging,
// kd-skip, bijective XCD h-band swizzle. launch_bounds(256,2).
// xq layout: [b][d4][hp194][ci32 grp 4][wp322][32B]
// wpk layout: [tap27][cc2][cq4][lane64][32B]

using f32x16 = __attribute__((ext_vector_type(16))) float;
using i32x8 = __attribute__((ext_vector_type(8))) int;
using i32x4 = __attribute__((ext_vector_type(4))) int;
typedef long long i64;
struct alignas(16) L2v { i64 x, y; };

namespace {
constexpr int Cc = 128, Dd = 4, Hh = 192, Ww = 320;
constexpr int HP = 194, WP = 322;
constexpr int NTAP = 27;
constexpr size_t PLANE = (size_t)4 * WP * 32;               // 41,216 B per (b,d,h) row-plane
constexpr size_t XQ_BYTES = (size_t)2 * Dd * HP * PLANE;    // 63,967,232
constexpr int ZA = 8 * 2 * 2576;
constexpr int ZB = 8 * 192 * 32;
constexpr int GSTR = WP * 32;                               // 10,304 B per ci32-group
constexpr int HB = 1056;                                    // 66*16 half-plane stride
constexpr int NU = 6 * 4 * 2 * 66;                          // 3168 16B staging units
constexpr int KDSTR = 9 * 2 * 4 * 64 * 32;                  // 147,456 B per kd in wpk
}

__global__ __launch_bounds__(256) void zero_pad_kernel(unsigned char* __restrict__ xq) {
  int i = blockIdx.x * 256 + threadIdx.x;
  if (i < ZA) {
    int bd = i / (2 * 2576);
    int r = i - bd * (2 * 2576);
    int hsel = r / 2576, seg = r - hsel * 2576;
    L2v z{0, 0};
    *(L2v*)(xq + ((size_t)bd * HP + (hsel ? 193 : 0)) * PLANE + (size_t)seg * 16) = z;
  } else if (i < ZA + ZB) {
    int j = i - ZA;
    int bd = j / (192 * 32);
    int r = j - bd * (192 * 32);
    int h = r / 32 + 1;
    int t = r & 31;
    int g = t >> 3, s2 = t & 7;
    int wsel = s2 >> 2, part = s2 & 3;
    *(i64*)(xq + ((size_t)bd * HP + h) * PLANE + (size_t)g * GSTR
            + (size_t)(wsel ? 321 : 0) * 32 + part * 8) = 0;
  }
}

__global__ __launch_bounds__(256) void qx_kernel(const float* __restrict__ x,
                                                 unsigned char* __restrict__ xq) {
  __shared__ unsigned char lt[64 * 136];
  const int tid = threadIdx.x;
  const int b = blockIdx.z >> 2, d = blockIdx.z & 3;
  const int h = blockIdx.y;
  const int w0 = blockIdx.x * 64;
  const int wl = tid & 63, cig = tid >> 6;
  const size_t cstr = (size_t)Dd * Hh * Ww;
  const float* xp = x + (((size_t)b * Cc * Dd + d) * Hh + h) * Ww + w0 + wl;
  #pragma unroll 4
  for (int i = 0; i < 32; ++i) {
    int ci = cig * 32 + i;
    __hip_fp8_e4m3 q(xp[ci * cstr]);
    lt[wl * 136 + ci] = q.__x;
  }
  __syncthreads();
  unsigned char* plane = xq + ((size_t)(b * Dd + d) * HP + h + 1) * PLANE;
  {
    int g = tid >> 6, w = tid & 63;
    const unsigned char* src = lt + w * 136 + g * 32;
    i64 a0 = *(const i64*)(src), a1 = *(const i64*)(src + 8);
    i64 a2 = *(const i64*)(src + 16), a3 = *(const i64*)(src + 24);
    unsigned char* dst = plane + (size_t)g * GSTR + (size_t)(w0 + 1 + w) * 32;
    *(L2v*)dst = L2v{a0, a1};
    *(L2v*)(dst + 16) = L2v{a2, a3};
  }
}

__global__ void wpack_kernel(const float* __restrict__ w, unsigned char* __restrict__ wpk) {
  int idx = blockIdx.x * 256 + threadIdx.x;
  if (idx >= Cc * Cc * NTAP) return;
  int tap = idx % NTAP;
  int t = idx / NTAP;
  int ci = t % Cc, co = t / Cc;
  int cc = ci >> 6, cq = co >> 5;
  int lane = (((ci >> 5) & 1) << 5) | (co & 31);
  __hip_fp8_e4m3 q(w[idx]);
  wpk[((((size_t)tap * 2 + cc) * 4 + cq) * 64 + lane) * 32 + (ci & 31)] = q.__x;
}

__device__ __forceinline__ void gll16(const unsigned char* g, unsigned char* l) {
  __builtin_amdgcn_global_load_lds(
      (const __attribute__((address_space(1))) void*)g,
      (__attribute__((address_space(3))) void*)l, 16, 0, 0);
}

__global__ __launch_bounds__(256, 2) void conv_mfma(const unsigned char* __restrict__ xq,
                                                    const unsigned char* __restrict__ wpk,
                                                    float* __restrict__ out) {
  __shared__ unsigned char lb[48 * HB];            // [hrow6][g4][half2][66w][16B] = 50,688 B
  const int tid = threadIdx.x;
  const int lane = tid & 63, wv = tid >> 6;
  const int l31 = lane & 31, chalf = lane >> 5;
  const int hr = wv >> 1, ch = wv & 1;             // wave: h-pair, cout-half (64 co)
  // ---- bijective XCD h-band swizzle: 1920 blocks, 240 per XCD ----
  const int id = blockIdx.x;
  const int xcd = id & 7, j = id >> 3;
  const int h0l = j / 40, rem = j - h0l * 40;
  const int z = rem / 5, wx = rem - z * 5;
  const int b = z >> 2, dout = z & 3;
  const int h0 = (xcd * 6 + h0l) * 4;              // 4 output h-rows per block
  const int w0 = wx * 64;
  const int kdmin = dout >= 2 ? 0 : 2 - dout;

  const long imgstep = (long)HP * PLANE;
  const long img0 = (long)(b * Dd + dout - 2) * imgstep;

  // A base: per-lane + cout-half part; tier/ct offsets compile-time
  const unsigned char* vbase = wpk + ch * 4096 + lane * 32;

  // B read bases (per kw); hr and chalf folded in; all further offsets imm
  const unsigned char* bb[3];
  #pragma unroll
  for (int kw = 0; kw < 3; ++kw)
    bb[kw] = lb + hr * (2 * 8 * HB) + chalf * (2 * HB) + (l31 + kw) * 16;

  f32x16 acc[2][2][2];                             // [hl][ct][nf] = 128 AGPR
  #pragma unroll
  for (int hl = 0; hl < 2; ++hl)
    #pragma unroll
    for (int a = 0; a < 2; ++a)
      #pragma unroll
      for (int n = 0; n < 2; ++n)
        #pragma unroll
        for (int r = 0; r < 16; ++r) acc[hl][a][n][r] = 0.f;

  for (int kd = kdmin; kd < 3; ++kd) {
    __syncthreads();                               // previous phase's reads done
    // ---- stage [hrow6][g4][half2][66w] for this kd via global_load_lds ----
    const unsigned char* img = xq + img0 + (long)kd * imgstep;
    for (int u = tid; u < NU; u += 256) {
      int w = u % 66;
      int rest = u / 66;                           // hrow*8 + g*2 + half
      int half = rest & 1, rg = rest >> 1;
      int g = rg & 3, hrow = rg >> 2;
      gll16(img + (size_t)(h0 + hrow) * PLANE + (size_t)g * GSTR
                + (size_t)(w0 + w) * 32 + half * 16,
            lb + u * 16);
    }
    __syncthreads();                               // drains vmcnt+lgkmcnt

    __builtin_amdgcn_s_setprio(1);
    #pragma unroll
    for (int kh = 0; kh < 3; ++kh)
      #pragma unroll
      for (int cc = 0; cc < 2; ++cc)
        #pragma unroll
        for (int kw = 0; kw < 3; ++kw) {
          // ---- A: 2 ct x 32B from L2/L1; reused over hl2 x nf2 = 4 MFMAs ----
          i32x8 av[2];
          #pragma unroll
          for (int ct = 0; ct < 2; ++ct)
            av[ct] = *(const i32x8*)(vbase + (size_t)kd * KDSTR
                + ((kh * 3 + kw) * 2 + cc) * 8192 + ct * 2048);
          #pragma unroll
          for (int hl = 0; hl < 2; ++hl)
            #pragma unroll
            for (int nf = 0; nf < 2; ++nf) {
              const int off = (hl + kh) * (8 * HB) + cc * (4 * HB) + nf * 512;
              i32x4 blo = *(const i32x4*)(bb[kw] + off);
              i32x4 bhi = *(const i32x4*)(bb[kw] + off + HB);
              i32x8 bv = __builtin_shufflevector(blo, bhi, 0, 1, 2, 3, 4, 5, 6, 7);
              #pragma unroll
              for (int ct = 0; ct < 2; ++ct)
                acc[hl][ct][nf] = __builtin_amdgcn_mfma_scale_f32_32x32x64_f8f6f4(
                    av[ct], bv, acc[hl][ct][nf], 0, 0, 0, 127, 0, 127);
            }
        }
    __builtin_amdgcn_s_setprio(0);
  }

  // ---- epilogue: col=l31 -> w, row=(reg&3)+8*(reg>>2)+4*chalf -> cout ----
  #pragma unroll
  for (int hl = 0; hl < 2; ++hl)
    #pragma unroll
    for (int ct = 0; ct < 2; ++ct)
      #pragma unroll
      for (int nf = 0; nf < 2; ++nf) {
        int ww = w0 + nf * 32 + l31;
        #pragma unroll
        for (int reg = 0; reg < 16; ++reg) {
          int co = ch * 64 + ct * 32 + (reg & 3) + 8 * (reg >> 2) + 4 * chalf;
          out[(((size_t)b * Cc + co) * Dd + dout) * (size_t)(Hh * Ww)
              + (size_t)(h0 + hr * 2 + hl) * Ww + ww] = acc[hl][ct][nf][reg];
        }
      }
}

extern "C" void kernel_launch(void* const* d_in, const int* in_sizes, int n_in,
                              void* d_out, int out_size, void* d_ws, size_t ws_size,
                              hipStream_t stream) {
  const float* x = (const float*)d_in[0];
  const float* w = (const float*)d_in[1];
  unsigned char* xq = (unsigned char*)d_ws;
  unsigned char* wpk = xq + XQ_BYTES;              // 442,368 B
  float* out = (float*)d_out;

  int nz = ZA + ZB;
  zero_pad_kernel<<<(nz + 255) / 256, 256, 0, stream>>>(xq);

  dim3 g1(Ww / 64, Hh, 2 * Dd);
  qx_kernel<<<g1, 256, 0, stream>>>(x, xq);

  int nw = Cc * Cc * NTAP;
  wpack_kernel<<<(nw + 255) / 256, 256, 0, stream>>>(w, wpk);

  conv_mfma<<<dim3(1920), 256, 0, stream>>>(xq, wpk, out);
}

// Round 14
// 222.925 us; speedup vs baseline: 7.0552x; 2.1234x over previous
//
#include <hip/hip_runtime.h>
#include <hip/hip_fp8.h>

// CausalConv3dFP8 round 14: r9 lean base (acc 64 AGPR, 4 blocks/CU) + explicit
// 2-deep A-fragment prefetch (rotating av[3][2], counted vmcnt(4/2/0)) so per-tier
// L2 latency hides under MFMAs. Raw s_barrier + lgkm-only drain pre-compute.
// Merged prep kernel. Split-half LDS, kd-skip, bijective XCD h-band swizzle.
// xq layout: [b][d4][hp194][ci32 grp 4][wp322][32B]
// wpk layout: [tap27][cc2][cq4][lane64][32B]

using f32x16 = __attribute__((ext_vector_type(16))) float;
using i32x8 = __attribute__((ext_vector_type(8))) int;
using i32x4 = __attribute__((ext_vector_type(4))) int;
typedef long long i64;
struct alignas(16) L2v { i64 x, y; };

namespace {
constexpr int Cc = 128, Dd = 4, Hh = 192, Ww = 320;
constexpr int HP = 194, WP = 322;
constexpr int NTAP = 27;
constexpr size_t PLANE = (size_t)4 * WP * 32;               // 41,216 B per (b,d,h) row-plane
constexpr size_t XQ_BYTES = (size_t)2 * Dd * HP * PLANE;    // 63,967,232
constexpr int ZA = 8 * 2 * 2576;                            // 41,216
constexpr int ZB = 8 * 192 * 32;                            // 49,152
constexpr int GSTR = WP * 32;                               // 10,304 B per ci32-group
constexpr int HB = 1056;                                    // 66*16 half-plane stride
constexpr int KDSTR = 9 * 2 * 4 * 64 * 32;                  // 147,456 B per kd in wpk
constexpr int NQX = 5 * 192 * 8;                            // 7680 qx blocks
constexpr int NZP = (ZA + ZB + 255) / 256;                  // 353 zero-pad blocks
constexpr int NWP = (Cc * Cc * NTAP + 255) / 256;           // 1728 wpack blocks
}

__global__ __launch_bounds__(256) void prep_kernel(const float* __restrict__ x,
                                                   const float* __restrict__ w,
                                                   unsigned char* __restrict__ xq,
                                                   unsigned char* __restrict__ wpk) {
  const int id = blockIdx.x;
  const int tid = threadIdx.x;
  if (id < NQX) {
    // ---- qx: quantize + channels-last transpose ----
    __shared__ unsigned char lt[64 * 136];
    const int wx = id % 5;
    const int h = (id / 5) % 192;
    const int bd = id / 960;
    const int b = bd >> 2, d = bd & 3;
    const int w0 = wx * 64;
    const int wl = tid & 63, cig = tid >> 6;
    const size_t cstr = (size_t)Dd * Hh * Ww;
    const float* xp = x + (((size_t)b * Cc * Dd + d) * Hh + h) * Ww + w0 + wl;
    #pragma unroll 4
    for (int i = 0; i < 32; ++i) {
      int ci = cig * 32 + i;
      __hip_fp8_e4m3 q(xp[ci * cstr]);
      lt[wl * 136 + ci] = q.__x;
    }
    __syncthreads();
    unsigned char* plane = xq + ((size_t)(b * Dd + d) * HP + h + 1) * PLANE;
    int g = tid >> 6, ww = tid & 63;
    const unsigned char* src = lt + ww * 136 + g * 32;
    i64 a0 = *(const i64*)(src), a1 = *(const i64*)(src + 8);
    i64 a2 = *(const i64*)(src + 16), a3 = *(const i64*)(src + 24);
    unsigned char* dst = plane + (size_t)g * GSTR + (size_t)(w0 + 1 + ww) * 32;
    *(L2v*)dst = L2v{a0, a1};
    *(L2v*)(dst + 16) = L2v{a2, a3};
  } else if (id < NQX + NZP) {
    // ---- zero_pad: h and w borders ----
    int i = (id - NQX) * 256 + tid;
    if (i < ZA) {
      int bd = i / (2 * 2576);
      int r = i - bd * (2 * 2576);
      int hsel = r / 2576, seg = r - hsel * 2576;
      L2v z{0, 0};
      *(L2v*)(xq + ((size_t)bd * HP + (hsel ? 193 : 0)) * PLANE + (size_t)seg * 16) = z;
    } else if (i < ZA + ZB) {
      int j = i - ZA;
      int bd = j / (192 * 32);
      int r = j - bd * (192 * 32);
      int h = r / 32 + 1;
      int t = r & 31;
      int g = t >> 3, s2 = t & 7;
      int wsel = s2 >> 2, part = s2 & 3;
      *(i64*)(xq + ((size_t)bd * HP + h) * PLANE + (size_t)g * GSTR
              + (size_t)(wsel ? 321 : 0) * 32 + part * 8) = 0;
    }
  } else {
    // ---- wpack ----
    int idx = (id - NQX - NZP) * 256 + tid;
    if (idx < Cc * Cc * NTAP) {
      int tap = idx % NTAP;
      int t = idx / NTAP;
      int ci = t % Cc, co = t / Cc;
      int cc = ci >> 6, cq = co >> 5;
      int lane = (((ci >> 5) & 1) << 5) | (co & 31);
      __hip_fp8_e4m3 q(w[idx]);
      wpk[((((size_t)tap * 2 + cc) * 4 + cq) * 64 + lane) * 32 + (ci & 31)] = q.__x;
    }
  }
}

__global__ __launch_bounds__(256, 2) void conv_mfma(const unsigned char* __restrict__ xq,
                                                    const unsigned char* __restrict__ wpk,
                                                    float* __restrict__ out) {
  __shared__ unsigned char lb[4 * 4 * 2 * HB];     // [hrow4][g4][half2][66w][16B] = 33,792 B
  const int tid = threadIdx.x;
  const int lane = tid & 63, wv = tid >> 6;
  const int l31 = lane & 31, chalf = lane >> 5;
  const int hr = wv >> 1, ch = wv & 1;             // wave: h-row, cout-half (64 co)
  // ---- bijective XCD h-band swizzle: 3840 blocks, 480/XCD ----
  const int id = blockIdx.x;
  const int xcd = id & 7, j = id >> 3;
  const int h0l = j / 40, rem = j - h0l * 40;
  const int z = rem / 5, wx = rem - z * 5;
  const int b = z >> 2, dout = z & 3;
  const int h0 = (xcd * 12 + h0l) * 2;
  const int w0 = wx * 64;
  const int kdmin = dout >= 2 ? 0 : 2 - dout;

  const long imgstep = (long)HP * PLANE;
  const long img0 = (long)(b * Dd + dout - 2) * imgstep;
  const unsigned char* vbase = wpk + ch * 4096 + lane * 32;

  const unsigned char* bb[3];
  #pragma unroll
  for (int kw = 0; kw < 3; ++kw)
    bb[kw] = lb + (hr * 4 + chalf) * 2 * HB + (l31 + kw) * 16;

  f32x16 acc[2][2];                                // [ct][nf] = 64 AGPR
  #pragma unroll
  for (int a = 0; a < 2; ++a)
    #pragma unroll
    for (int n = 0; n < 2; ++n)
      #pragma unroll
      for (int r = 0; r < 16; ++r) acc[a][n][r] = 0.f;

  i32x8 av[3][2];                                  // rotating 2-deep A prefetch

  for (int kd = kdmin; kd < 3; ++kd) {
    __syncthreads();                               // prev compute done; buffer free
    // ---- stage [hrow4][g4][half2][66w] for this kd (sync reg-staged) ----
    const unsigned char* img = xq + img0 + (long)kd * imgstep;
    for (int u = tid; u < 1056; u += 256) {
      int w = u % 66, rest = u / 66;
      int g = rest & 3, hrow = rest >> 2;
      const unsigned char* src = img + (size_t)(h0 + hrow) * PLANE
          + (size_t)g * GSTR + (size_t)(w0 + w) * 32;
      L2v lo = *(const L2v*)src;
      L2v hi = *(const L2v*)(src + 16);
      unsigned char* base = lb + (hrow * 4 + g) * 2 * HB + w * 16;
      *(L2v*)(base) = lo;
      *(L2v*)(base + HB) = hi;
    }
    // ---- prefetch tiers 0,1 A-frags; they fly across the barrier ----
    const unsigned char* wkd = vbase + (size_t)kd * KDSTR;
    #pragma unroll
    for (int t = 0; t < 2; ++t) {                  // tier t: kh=t/6, cc=(t/3)%2, kw=t%3
      const int kh = t / 6, cc = (t / 3) % 2, kw = t % 3;
      #pragma unroll
      for (int ct = 0; ct < 2; ++ct)
        av[t][ct] = *(const i32x8*)(wkd + (kh * 3 + kw) * 16384 + cc * 8192 + ct * 2048);
    }
    asm volatile("s_waitcnt lgkmcnt(0)" ::: "memory");  // ds_writes visible; avs in flight
    __builtin_amdgcn_s_barrier();
    __builtin_amdgcn_sched_barrier(0);

    __builtin_amdgcn_s_setprio(1);
    #pragma unroll
    for (int t = 0; t < 18; ++t) {
      const int kh = t / 6, cc = (t / 3) % 2, kw = t % 3;
      // ---- issue tier t+2's A-loads into rotating slot ----
      if (t < 16) {
        const int tp = t + 2;
        const int khp = tp / 6, ccp = (tp / 3) % 2, kwp = tp % 3;
        #pragma unroll
        for (int ct = 0; ct < 2; ++ct)
          av[tp % 3][ct] =
              *(const i32x8*)(wkd + (khp * 3 + kwp) * 16384 + ccp * 8192 + ct * 2048);
      }
      // ---- B fragments (LDS) for this tier ----
      i32x8 bv[2];
      #pragma unroll
      for (int nf = 0; nf < 2; ++nf) {
        const int off = (kh * 4 + cc * 2) * 2 * HB + nf * 512;
        i32x4 blo = *(const i32x4*)(bb[kw] + off);
        i32x4 bhi = *(const i32x4*)(bb[kw] + off + HB);
        bv[nf] = __builtin_shufflevector(blo, bhi, 0, 1, 2, 3, 4, 5, 6, 7);
      }
      // ---- waits: tier t's A done (keep 2 pairs in flight); LDS done ----
      if (t < 16)      asm volatile("s_waitcnt vmcnt(4)" ::: "memory");
      else if (t == 16) asm volatile("s_waitcnt vmcnt(2)" ::: "memory");
      else              asm volatile("s_waitcnt vmcnt(0)" ::: "memory");
      asm volatile("s_waitcnt lgkmcnt(0)" ::: "memory");
      __builtin_amdgcn_sched_barrier(0);
      #pragma unroll
      for (int nf = 0; nf < 2; ++nf)
        #pragma unroll
        for (int ct = 0; ct < 2; ++ct)
          acc[ct][nf] = __builtin_amdgcn_mfma_scale_f32_32x32x64_f8f6f4(
              av[t % 3][ct], bv[nf], acc[ct][nf], 0, 0, 0, 127, 0, 127);
    }
    __builtin_amdgcn_s_setprio(0);
  }

  // ---- epilogue: col=l31 -> w, row=(reg&3)+8*(reg>>2)+4*chalf -> cout ----
  #pragma unroll
  for (int ct = 0; ct < 2; ++ct)
    #pragma unroll
    for (int nf = 0; nf < 2; ++nf) {
      int ww = w0 + nf * 32 + l31;
      #pragma unroll
      for (int reg = 0; reg < 16; ++reg) {
        int co = ch * 64 + ct * 32 + (reg & 3) + 8 * (reg >> 2) + 4 * chalf;
        out[(((size_t)b * Cc + co) * Dd + dout) * (size_t)(Hh * Ww)
            + (size_t)(h0 + hr) * Ww + ww] = acc[ct][nf][reg];
      }
    }
}

extern "C" void kernel_launch(void* const* d_in, const int* in_sizes, int n_in,
                              void* d_out, int out_size, void* d_ws, size_t ws_size,
                              hipStream_t stream) {
  const float* x = (const float*)d_in[0];
  const float* w = (const float*)d_in[1];
  unsigned char* xq = (unsigned char*)d_ws;
  unsigned char* wpk = xq + XQ_BYTES;              // 442,368 B
  float* out = (float*)d_out;

  prep_kernel<<<dim3(NQX + NZP + NWP), 256, 0, stream>>>(x, w, xq, wpk);
  conv_mfma<<<dim3(3840), 256, 0, stream>>>(xq, wpk, out);
}